// Round 5
// baseline (344.426 us; speedup 1.0000x reference)
//
#include <hip/hip_runtime.h>

#define IDIM   256
#define HDIM   64
#define BATCH  1024
#define NITEMS 200
#define NCOLS  (IDIM * HDIM)   // 16384

typedef __bf16 bf16x8 __attribute__((ext_vector_type(8)));
typedef float  f32x4  __attribute__((ext_vector_type(4)));

__device__ __forceinline__ unsigned short f2bf(float f) {
    unsigned int u = __float_as_uint(f);
    u += 0x7FFFu + ((u >> 16) & 1u);   // round-to-nearest-even
    return (unsigned short)(u >> 16);
}

// fast tanh: 1 - 2/(e^{2x}+1); v_exp+v_rcp, saturates correctly (rcp(inf)=0)
__device__ __forceinline__ float fast_tanh(float x) {
    float e2 = __expf(2.0f * x);
    return 1.0f - 2.0f * __builtin_amdgcn_rcpf(e2 + 1.0f);
}

// ---- merged prep: blocks [0,4096): W_q transpose+cvt; [4096,4352): query cvt ----
__global__ __launch_bounds__(256) void k_prep(const float* __restrict__ Wq,
                                              const float* __restrict__ q,
                                              unsigned short* __restrict__ Bt,
                                              unsigned short* __restrict__ Aq) {
    int bx = blockIdx.x;
    if (bx < 4096) {
        __shared__ float tile[32][33];
        int n0 = (bx & 511) * 32;          // 512 n-tiles
        int k0 = (bx >> 9) * 32;           // 8 k-tiles
        int tx = threadIdx.x & 31;
        int ty = threadIdx.x >> 5;         // 0..7
#pragma unroll
        for (int j = 0; j < 32; j += 8)
            tile[ty + j][tx] = Wq[(size_t)(k0 + ty + j) * NCOLS + n0 + tx];
        __syncthreads();
#pragma unroll
        for (int j = 0; j < 32; j += 8)
            Bt[(size_t)(n0 + ty + j) * IDIM + k0 + tx] = f2bf(tile[tx][ty + j]);
    } else {
        int idx = (bx - 4096) * 256 + threadIdx.x;   // 65536 float4s
        float4 f = ((const float4*)q)[idx];
        ushort4 o;
        o.x = f2bf(f.x); o.y = f2bf(f.y); o.z = f2bf(f.z); o.w = f2bf(f.w);
        ((ushort4*)Aq)[idx] = o;
    }
}

// ---- GEMM: P = Aq(1024x256) @ Wq(256x16384), fused bias+tanh+W_r reduce ->
//      V[b][i] = sum_h tanh(P[b, i*64+h] + b_q) * W_r[h]   (V: 1024x256 f32)
// One wave computes a 64(m) x 64(n) C tile. unroll 2 + (256,3): bounded
// VGPR (~170) -> 3 waves/SIMD guaranteed, loads pipelined 2 k-steps deep.
__global__ __launch_bounds__(256, 3) void k_gemm_v(const unsigned short* __restrict__ Aq,
                                                   const unsigned short* __restrict__ Bt,
                                                   const float* __restrict__ bq,
                                                   const float* __restrict__ Wr,
                                                   float* __restrict__ V) {
    int w    = threadIdx.x >> 6;
    int lane = threadIdx.x & 63;
    int l16  = lane & 15;
    int quad = lane >> 4;
    int blk  = blockIdx.x;             // 1024 blocks
    int bn   = blk & 127;              // 128 n-blocks (each 2 n-tiles)
    int bm   = blk >> 7;               // 8 m-blocks  (each 2 m-tiles)
    int m_tile = bm * 2 + (w & 1);     // 0..15
    int n_tile = bn * 2 + (w >> 1);    // 0..255
    int m_base = m_tile * 64;
    int n_base = n_tile * 64;

    f32x4 acc[4][4] = {};
    const unsigned short* Ap = Aq + (size_t)(m_base + l16) * IDIM + quad * 8;
    const unsigned short* Bp = Bt + (size_t)(n_base + l16) * IDIM + quad * 8;

    // epilogue operands loaded early (L2-hot, independent of the K-loop)
    float bv[4], wr[4];
#pragma unroll
    for (int nt = 0; nt < 4; nt++) {
        int nl = nt * 16 + l16;
        bv[nt] = bq[n_base + nl];
        wr[nt] = Wr[nl];
    }

#pragma unroll 2
    for (int k0 = 0; k0 < IDIM; k0 += 32) {
        bf16x8 a[4], b[4];
#pragma unroll
        for (int t = 0; t < 4; t++) a[t] = *(const bf16x8*)(Ap + (size_t)t * 16 * IDIM + k0);
#pragma unroll
        for (int t = 0; t < 4; t++) b[t] = *(const bf16x8*)(Bp + (size_t)t * 16 * IDIM + k0);
#pragma unroll
        for (int mt = 0; mt < 4; mt++)
#pragma unroll
            for (int nt = 0; nt < 4; nt++)
                acc[mt][nt] = __builtin_amdgcn_mfma_f32_16x16x32_bf16(a[mt], b[nt], acc[mt][nt], 0, 0, 0);
    }

    int i = n_tile;
#pragma unroll
    for (int mt = 0; mt < 4; mt++) {
#pragma unroll
        for (int reg = 0; reg < 4; reg++) {
            float s = 0.0f;
#pragma unroll
            for (int nt = 0; nt < 4; nt++) {
                float c = acc[mt][nt][reg] + bv[nt];
                s += fast_tanh(c) * wr[nt];
            }
            // reduce over the 16 lanes (l16) of this quad-row group
            s += __shfl_xor(s, 1);
            s += __shfl_xor(s, 2);
            s += __shfl_xor(s, 4);
            s += __shfl_xor(s, 8);
            if (l16 == 0) {
                int m = m_base + mt * 16 + quad * 4 + reg;   // D row = quad*4+reg
                V[m * IDIM + i] = s;
            }
        }
    }
}

// ---- fused score -> exp -> weighted accumulate, single pass over item ----
// one item per quad (16 lanes), 2 in flight per quad, 8 per wave.
__global__ __launch_bounds__(256) void k_score(const float* __restrict__ item,
                                               const float* __restrict__ V,
                                               float* __restrict__ out) {
    __shared__ float lacc[16][IDIM];   // 16 KB partials
    __shared__ float lS[16];
    int b    = blockIdx.x;
    int tid  = threadIdx.x;
    int wid  = tid >> 6;
    int lane = tid & 63;
    int l16  = lane & 15;
    int quad = lane >> 4;

    const float4* itemB = (const float4*)(item + (size_t)b * NITEMS * IDIM);
    const float4* Vb    = (const float4*)(V + (size_t)b * IDIM);

    float4 v[4];
#pragma unroll
    for (int c = 0; c < 4; c++) v[c] = Vb[l16 + 16 * c];

    float4 acc[4];
#pragma unroll
    for (int c = 0; c < 4; c++) acc[c] = make_float4(0.f, 0.f, 0.f, 0.f);
    float S = 0.f;

    for (int chunk = wid; chunk < 25; chunk += 4) {
        int r0 = chunk * 8 + quad;       // item for x0
        int r1 = r0 + 4;                 // item for x1 (max 199)
        float4 x0[4], x1[4];
#pragma unroll
        for (int c = 0; c < 4; c++) x0[c] = itemB[(size_t)r0 * 64 + l16 + 16 * c];
#pragma unroll
        for (int c = 0; c < 4; c++) x1[c] = itemB[(size_t)r1 * 64 + l16 + 16 * c];

        float d0 = 0.f, d1 = 0.f;
#pragma unroll
        for (int c = 0; c < 4; c++) {
            d0 += x0[c].x * v[c].x + x0[c].y * v[c].y + x0[c].z * v[c].z + x0[c].w * v[c].w;
            d1 += x1[c].x * v[c].x + x1[c].y * v[c].y + x1[c].z * v[c].z + x1[c].w * v[c].w;
        }
#pragma unroll
        for (int m = 1; m < 16; m <<= 1) {
            d0 += __shfl_xor(d0, m);
            d1 += __shfl_xor(d1, m);
        }
        float e0 = __expf(d0);
        float e1 = __expf(d1);
        S += e0 + e1;
#pragma unroll
        for (int c = 0; c < 4; c++) {
            acc[c].x += e0 * x0[c].x + e1 * x1[c].x;
            acc[c].y += e0 * x0[c].y + e1 * x1[c].y;
            acc[c].z += e0 * x0[c].z + e1 * x1[c].z;
            acc[c].w += e0 * x0[c].w + e1 * x1[c].w;
        }
    }

    int row = wid * 4 + quad;            // 16 partial rows
#pragma unroll
    for (int c = 0; c < 4; c++)
        ((float4*)&lacc[row][0])[l16 + 16 * c] = acc[c];
    if (l16 == 0) lS[row] = S;
    __syncthreads();

    float s = 0.f;
#pragma unroll
    for (int i = 0; i < 16; i++) s += lacc[i][tid];
    float Stot = 0.f;
#pragma unroll
    for (int i = 0; i < 16; i++) Stot += lS[i];
    out[(size_t)b * IDIM + tid] = s / (1.0f + Stot);
}

extern "C" void kernel_launch(void* const* d_in, const int* in_sizes, int n_in,
                              void* d_out, int out_size, void* d_ws, size_t ws_size,
                              hipStream_t stream) {
    const float* item  = (const float*)d_in[0];
    const float* query = (const float*)d_in[1];
    const float* Wq    = (const float*)d_in[2];
    const float* bq    = (const float*)d_in[3];
    const float* Wr    = (const float*)d_in[4];
    float* out = (float*)d_out;

    char* ws = (char*)d_ws;
    unsigned short* Aq = (unsigned short*)ws;                          // 512 KB
    unsigned short* Bt = (unsigned short*)(ws + (512 << 10));          // 8 MB
    float*          V  = (float*)(ws + (512 << 10) + (8 << 20));       // 1 MB

    k_prep   <<<4352, 256, 0, stream>>>(Wq, query, Bt, Aq);
    k_gemm_v <<<1024, 256, 0, stream>>>(Aq, Bt, bq, Wr, V);
    k_score  <<<1024, 256, 0, stream>>>(item, V, out);
}